// Round 3
// baseline (362.234 us; speedup 1.0000x reference)
//
#include <hip/hip_runtime.h>
#include <hip/hip_bf16.h>

typedef __bf16 bf16x8 __attribute__((ext_vector_type(8)));
typedef unsigned short u16x8 __attribute__((ext_vector_type(8)));
typedef float f32x4 __attribute__((ext_vector_type(4)));
typedef __hip_bfloat16 hbf;

static constexpr int B = 4, T = 512, D = 1024, N = 16, H = 256;
static constexpr size_t E_ELEMS = (size_t)B * N * T * D;    // 33,554,432
static constexpr size_t ATTN_ELEMS = (size_t)B * N * T * T; // 16,777,216

__device__ __forceinline__ bf16x8 load8(const hbf* p) {
  return *reinterpret_cast<const bf16x8*>(p);
}

__device__ __forceinline__ unsigned short f2bf(float f) {
  union { __hip_bfloat16 h; unsigned short u; } cv;
  cv.h = __float2bfloat16(f);
  return cv.u;
}

// async global->LDS, 16B per lane; lds dest must be waveBase + lane*16
__device__ __forceinline__ void gload16(const hbf* g, hbf* l) {
  __builtin_amdgcn_global_load_lds(
      (const __attribute__((address_space(1))) void*)g,
      (__attribute__((address_space(3))) void*)l, 16, 0, 0);
}

// ---------------- fp32 -> bf16 row-major cast (8 elems / thread) -------------
__global__ __launch_bounds__(256) void cast_bf_k(const float* __restrict__ in,
                                                 unsigned short* __restrict__ out,
                                                 int n8) {
  int i = blockIdx.x * 256 + threadIdx.x;
  if (i >= n8) return;
  const float4* p = reinterpret_cast<const float4*>(in) + (size_t)i * 2;
  float4 a = p[0], b = p[1];
  u16x8 v;
  v[0] = f2bf(a.x); v[1] = f2bf(a.y); v[2] = f2bf(a.z); v[3] = f2bf(a.w);
  v[4] = f2bf(b.x); v[5] = f2bf(b.y); v[6] = f2bf(b.z); v[7] = f2bf(b.w);
  reinterpret_cast<u16x8*>(out)[i] = v;
}

// ------------- batched transpose+cast: in[z][r][c] fp32 -> out[z][c][r] bf16 -
__global__ void transpose_cast_k(const float* __restrict__ in,
                                 unsigned short* __restrict__ out, int R, int C) {
  __shared__ unsigned short tile[32][33];
  int z = blockIdx.z;
  int c0 = blockIdx.x * 32, r0 = blockIdx.y * 32;
  const float* inz = in + (size_t)z * R * C;
  unsigned short* outz = out + (size_t)z * R * C;
  int tx = threadIdx.x, ty = threadIdx.y;
  for (int i = ty; i < 32; i += 8)
    tile[i][tx] = f2bf(inz[(size_t)(r0 + i) * C + (c0 + tx)]);
  __syncthreads();
  for (int i = ty; i < 32; i += 8)
    outz[(size_t)(c0 + i) * R + (r0 + tx)] = tile[tx][i];
}

// =========== stage A: wq[b][n][t][h] = sum_d x[b][t][d] * w[n][d][h] =========
// 128x128x(BK=32), 3-buffer pipeline, counted vmcnt (T4): L(k+1),L(k+2) stay
// in flight across the barrier; only the last step drains to 0.
__global__ __launch_bounds__(256) void gemm_wq_tiled(const hbf* __restrict__ xb,
                                                     const hbf* __restrict__ wT,
                                                     hbf* __restrict__ wq) {
  __shared__ __align__(16) hbf As[3][128 * 32];
  __shared__ __align__(16) hbf Bs[3][128 * 32];
  int idx = blockIdx.x;                 // b*128 + mt*32 + jt
  int b = idx >> 7, mt = (idx >> 5) & 3, jt = idx & 31;
  const hbf* A = xb + (size_t)b * T * D + (size_t)mt * 128 * D;
  const hbf* Bp = wT + (size_t)jt * 128 * D;
  int tid = threadIdx.x, wave = tid >> 6, lane = tid & 63;
  int col = lane & 15, quad = lane >> 4;
  int wm = wave & 1, wn = wave >> 1;
  const hbf* stG = (wave < 2) ? A : Bp;  // waves 0,1 stage A; 2,3 stage B
  int ibase = (wave & 1) * 4;            // 4 issues x 64 slots each

  auto STAGE = [&](int kt, int bi) {
    hbf* stL = (wave < 2) ? As[bi] : Bs[bi];
#pragma unroll
    for (int j = 0; j < 4; ++j) {
      int slot = (ibase + j) * 64 + lane;
      int row = slot >> 2, kc = slot & 3;
      gload16(stG + (size_t)row * D + kt * 32 + kc * 8, stL + slot * 8);
    }
  };

  f32x4 acc[4][4] = {};
  constexpr int NT = D / 32;  // 32
  STAGE(0, 0);
  STAGE(1, 1);
  for (int k = 0; k < NT; ++k) {
    int cb = k % 3;
    if (k == NT - 1)
      asm volatile("s_waitcnt vmcnt(0)" ::: "memory");
    else
      asm volatile("s_waitcnt vmcnt(4)" ::: "memory");  // L(k) done; L(k+1) in flight
    __builtin_amdgcn_s_barrier();
    if (k + 2 < NT) STAGE(k + 2, (k + 2) % 3);
    bf16x8 a[4], bb[4];
#pragma unroll
    for (int s = 0; s < 4; ++s)
      a[s] = load8(As[cb] + (wm * 64 + s * 16 + col) * 32 + quad * 8);
#pragma unroll
    for (int t = 0; t < 4; ++t)
      bb[t] = load8(Bs[cb] + (wn * 64 + t * 16 + col) * 32 + quad * 8);
#pragma unroll
    for (int s = 0; s < 4; ++s)
#pragma unroll
      for (int t = 0; t < 4; ++t)
        acc[s][t] = __builtin_amdgcn_mfma_f32_16x16x32_bf16(a[s], bb[t], acc[s][t], 0, 0, 0);
  }
  hbf* wqb = wq + (size_t)b * 16 * T * H;
#pragma unroll
  for (int s = 0; s < 4; ++s) {
    int row = mt * 128 + wm * 64 + s * 16 + quad * 4;
#pragma unroll
    for (int t = 0; t < 4; ++t) {
      int j = jt * 128 + wn * 64 + t * 16 + col;
      int n = j >> 8, h = j & 255;
      hbf* dst = wqb + (size_t)n * T * H + (size_t)row * H + h;
#pragma unroll
      for (int r = 0; r < 4; ++r)
        dst[(size_t)r * H] = __float2bfloat16(acc[s][t][r]);
    }
  }
}

// ------- stage B: S = wq_bn @ wq_bn^T (16 rows/block), softmax,
//         write attn fp32 to d_out (output 1) and bf16 to ws (stage-C operand)
__global__ __launch_bounds__(256) void attn_k(const hbf* __restrict__ wq,
                                              float* __restrict__ attn_f,
                                              hbf* __restrict__ attn_b) {
  __shared__ float S[16][516];  // +4 pad
  int blk = blockIdx.x;        // 2048 blocks
  int bn = blk >> 5;
  int mt = blk & 31;
  const hbf* Wq = wq + (size_t)bn * T * H;
  int wave = threadIdx.x >> 6, lane = threadIdx.x & 63;
  int col = lane & 15, quad = lane >> 4;
  int m0 = mt * 16;
  f32x4 acc[8] = {};
  for (int k0 = 0; k0 < H; k0 += 32) {
    int k = k0 + quad * 8;
    bf16x8 afrag = load8(Wq + (size_t)(m0 + col) * H + k);
#pragma unroll
    for (int t = 0; t < 8; ++t) {
      int jrow = wave * 128 + t * 16 + col;
      bf16x8 bfrag = load8(Wq + (size_t)jrow * H + k);
      acc[t] = __builtin_amdgcn_mfma_f32_16x16x32_bf16(afrag, bfrag, acc[t], 0, 0, 0);
    }
  }
#pragma unroll
  for (int t = 0; t < 8; ++t)
#pragma unroll
    for (int r = 0; r < 4; ++r)
      S[quad * 4 + r][wave * 128 + t * 16 + col] = acc[t][r];
  __syncthreads();
  for (int rr = 0; rr < 4; ++rr) {
    int row = wave * 4 + rr;
    float v[8];
    float mx = -1e30f;
#pragma unroll
    for (int i = 0; i < 8; ++i) { v[i] = S[row][lane + i * 64]; mx = fmaxf(mx, v[i]); }
#pragma unroll
    for (int off = 32; off > 0; off >>= 1) mx = fmaxf(mx, __shfl_xor(mx, off));
    float sum = 0.f;
#pragma unroll
    for (int i = 0; i < 8; ++i) { v[i] = __expf(v[i] - mx); sum += v[i]; }
#pragma unroll
    for (int off = 32; off > 0; off >>= 1) sum += __shfl_xor(sum, off);
    float inv = 1.0f / sum;
    size_t base = ((size_t)bn * T + m0 + row) * T;
    float* dst = attn_f + base;
    hbf* dstb = attn_b + base;
#pragma unroll
    for (int i = 0; i < 8; ++i) {
      float p = v[i] * inv;
      dst[lane + i * 64] = p;
      dstb[lane + i * 64] = __float2bfloat16(p);
    }
  }
}

// =========== stage C: e[bn][s][d] = sum_t attn[bn][s][t] * x[b][t][d] ========
// 128x128x(BK=32), 3-buffer pipeline, counted vmcnt (T4). A = attn_b[bn]
// [512][512]; B = xT[b] [1024][512] (k-contiguous). 2048 blocks. fp32 out.
__global__ __launch_bounds__(256) void gemm_out_tiled(const hbf* __restrict__ attn,
                                                      const hbf* __restrict__ xT,
                                                      float* __restrict__ eout) {
  __shared__ __align__(16) hbf As[3][128 * 32];
  __shared__ __align__(16) hbf Bs[3][128 * 32];
  int idx = blockIdx.x;                 // bn*32 + mt*8 + nt
  int bn = idx >> 5, mt = (idx >> 3) & 3, nt = idx & 7;
  int b = bn >> 4;
  const hbf* A = attn + (size_t)bn * T * T + (size_t)mt * 128 * T;
  const hbf* Bp = xT + (size_t)b * D * T + (size_t)nt * 128 * T;
  float* C = eout + (size_t)bn * T * D;
  int tid = threadIdx.x, wave = tid >> 6, lane = tid & 63;
  int col = lane & 15, quad = lane >> 4;
  int wm = wave & 1, wn = wave >> 1;
  const hbf* stG = (wave < 2) ? A : Bp;
  int ibase = (wave & 1) * 4;

  auto STAGE = [&](int kt, int bi) {
    hbf* stL = (wave < 2) ? As[bi] : Bs[bi];
#pragma unroll
    for (int j = 0; j < 4; ++j) {
      int slot = (ibase + j) * 64 + lane;
      int row = slot >> 2, kc = slot & 3;
      gload16(stG + (size_t)row * T + kt * 32 + kc * 8, stL + slot * 8);
    }
  };

  f32x4 acc[4][4] = {};
  constexpr int NT = T / 32;  // 16
  STAGE(0, 0);
  STAGE(1, 1);
  for (int k = 0; k < NT; ++k) {
    int cb = k % 3;
    if (k == NT - 1)
      asm volatile("s_waitcnt vmcnt(0)" ::: "memory");
    else
      asm volatile("s_waitcnt vmcnt(4)" ::: "memory");
    __builtin_amdgcn_s_barrier();
    if (k + 2 < NT) STAGE(k + 2, (k + 2) % 3);
    bf16x8 a[4], bb[4];
#pragma unroll
    for (int s = 0; s < 4; ++s)
      a[s] = load8(As[cb] + (wm * 64 + s * 16 + col) * 32 + quad * 8);
#pragma unroll
    for (int t = 0; t < 4; ++t)
      bb[t] = load8(Bs[cb] + (wn * 64 + t * 16 + col) * 32 + quad * 8);
#pragma unroll
    for (int s = 0; s < 4; ++s)
#pragma unroll
      for (int t = 0; t < 4; ++t)
        acc[s][t] = __builtin_amdgcn_mfma_f32_16x16x32_bf16(a[s], bb[t], acc[s][t], 0, 0, 0);
  }
#pragma unroll
  for (int s = 0; s < 4; ++s) {
    int row = mt * 128 + wm * 64 + s * 16 + quad * 4;
#pragma unroll
    for (int t = 0; t < 4; ++t) {
      int d = nt * 128 + wn * 64 + t * 16 + col;
      float* dst = C + (size_t)row * D + d;
#pragma unroll
      for (int r = 0; r < 4; ++r)
        dst[(size_t)r * D] = acc[s][t][r];
    }
  }
}

extern "C" void kernel_launch(void* const* d_in, const int* in_sizes, int n_in,
                              void* d_out, int out_size, void* d_ws, size_t ws_size,
                              hipStream_t stream) {
  const float* x = (const float*)d_in[0];     // [B,T,D] fp32
  const float* w_qs = (const float*)d_in[1];  // [N,D,H] fp32 (w_ks unused per source bug)
  float* e_out = (float*)d_out;               // [B,N,T,D] fp32
  float* attn_out = e_out + E_ELEMS;          // [B,N,T,T] fp32

  char* ws = (char*)d_ws;
  hbf* x_bf = (hbf*)ws;                          // [B,T,D]   4 MB
  hbf* xT   = (hbf*)(ws + (4u << 20));           // [B,D,T]   4 MB
  hbf* wT   = (hbf*)(ws + (8u << 20));           // [N,H,D]   8 MB
  hbf* wq   = (hbf*)(ws + (16u << 20));          // [B*N,T,H] 16 MB
  hbf* attn_b = (hbf*)(ws + (32u << 20));        // [B*N,T,T] 32 MB

  dim3 tb(32, 8);
  cast_bf_k<<<1024, 256, 0, stream>>>(x, (unsigned short*)x_bf, (B * T * D) / 8);
  transpose_cast_k<<<dim3(H / 32, D / 32, N), tb, 0, stream>>>(
      w_qs, (unsigned short*)wT, D, H);
  transpose_cast_k<<<dim3(D / 32, T / 32, B), tb, 0, stream>>>(
      x, (unsigned short*)xT, T, D);
  gemm_wq_tiled<<<512, 256, 0, stream>>>(x_bf, wT, wq);
  attn_k<<<2048, 256, 0, stream>>>(wq, attn_out, attn_b);
  gemm_out_tiled<<<2048, 256, 0, stream>>>(attn_b, xT, e_out);
}

// Round 4
// 335.617 us; speedup vs baseline: 1.0793x; 1.0793x over previous
//
#include <hip/hip_runtime.h>
#include <hip/hip_bf16.h>

typedef __bf16 bf16x8 __attribute__((ext_vector_type(8)));
typedef unsigned short u16x8 __attribute__((ext_vector_type(8)));
typedef float f32x4 __attribute__((ext_vector_type(4)));
typedef __hip_bfloat16 hbf;

static constexpr int B = 4, T = 512, D = 1024, N = 16, H = 256;
static constexpr size_t E_ELEMS = (size_t)B * N * T * D;    // 33,554,432
static constexpr size_t ATTN_ELEMS = (size_t)B * N * T * T; // 16,777,216

__device__ __forceinline__ bf16x8 load8(const hbf* p) {
  return *reinterpret_cast<const bf16x8*>(p);
}

__device__ __forceinline__ unsigned short f2bf(float f) {
  union { __hip_bfloat16 h; unsigned short u; } cv;
  cv.h = __float2bfloat16(f);
  return cv.u;
}

// async global->LDS, 16B per lane; lds dest must be waveBase + lane*16
__device__ __forceinline__ void gload16(const hbf* g, hbf* l) {
  __builtin_amdgcn_global_load_lds(
      (const __attribute__((address_space(1))) void*)g,
      (__attribute__((address_space(3))) void*)l, 16, 0, 0);
}

// ---------------- fp32 -> bf16 row-major cast (8 elems / thread) -------------
__global__ __launch_bounds__(256) void cast_bf_k(const float* __restrict__ in,
                                                 unsigned short* __restrict__ out,
                                                 int n8) {
  int i = blockIdx.x * 256 + threadIdx.x;
  if (i >= n8) return;
  const float4* p = reinterpret_cast<const float4*>(in) + (size_t)i * 2;
  float4 a = p[0], b = p[1];
  u16x8 v;
  v[0] = f2bf(a.x); v[1] = f2bf(a.y); v[2] = f2bf(a.z); v[3] = f2bf(a.w);
  v[4] = f2bf(b.x); v[5] = f2bf(b.y); v[6] = f2bf(b.z); v[7] = f2bf(b.w);
  reinterpret_cast<u16x8*>(out)[i] = v;
}

// ------------- batched transpose+cast: in[z][r][c] fp32 -> out[z][c][r] bf16 -
__global__ void transpose_cast_k(const float* __restrict__ in,
                                 unsigned short* __restrict__ out, int R, int C) {
  __shared__ unsigned short tile[32][33];
  int z = blockIdx.z;
  int c0 = blockIdx.x * 32, r0 = blockIdx.y * 32;
  const float* inz = in + (size_t)z * R * C;
  unsigned short* outz = out + (size_t)z * R * C;
  int tx = threadIdx.x, ty = threadIdx.y;
  for (int i = ty; i < 32; i += 8)
    tile[i][tx] = f2bf(inz[(size_t)(r0 + i) * C + (c0 + tx)]);
  __syncthreads();
  for (int i = ty; i < 32; i += 8)
    outz[(size_t)(c0 + i) * R + (r0 + tx)] = tile[tx][i];
}

// =========== stage A: wq[b][n][t][h] = sum_d x[b][t][d] * w[n][d][h] =========
// 128x64x(BK=32) LDS-tiled, 2-phase dbuf. Retiled from 128x128 to lift the
// grid from 512 blocks (2/CU, latency-exposed) to 1024 (4/CU).
__global__ __launch_bounds__(256) void gemm_wq_tiled(const hbf* __restrict__ xb,
                                                     const hbf* __restrict__ wT,
                                                     hbf* __restrict__ wq) {
  __shared__ __align__(16) hbf As[2][128 * 32];
  __shared__ __align__(16) hbf Bs[2][64 * 32];
  int idx = blockIdx.x;                 // b*256 + mt*64 + jt
  int b = idx >> 8, mt = (idx >> 6) & 3, jt = idx & 63;
  const hbf* A = xb + (size_t)b * T * D + (size_t)mt * 128 * D;
  const hbf* Bp = wT + (size_t)jt * 64 * D;
  int tid = threadIdx.x, wave = tid >> 6, lane = tid & 63;
  int col = lane & 15, quad = lane >> 4;
  int wm = wave & 1, wn = wave >> 1;

  auto STAGE = [&](int k0, int bi) {
    if (wave < 2) {  // A: 8 KB = 8 wave-issues, waves 0,1 x 4
#pragma unroll
      for (int j = 0; j < 4; ++j) {
        int slot = (wave * 4 + j) * 64 + lane;
        int row = slot >> 2, kc = slot & 3;
        gload16(A + (size_t)row * D + k0 + kc * 8, As[bi] + slot * 8);
      }
    } else {  // B: 4 KB = 4 wave-issues, waves 2,3 x 2
#pragma unroll
      for (int j = 0; j < 2; ++j) {
        int slot = ((wave - 2) * 2 + j) * 64 + lane;
        int row = slot >> 2, kc = slot & 3;
        gload16(Bp + (size_t)row * D + k0 + kc * 8, Bs[bi] + slot * 8);
      }
    }
  };

  f32x4 acc[4][2] = {};
  STAGE(0, 0);
  int cur = 0;
  for (int k0 = 0; k0 < D; k0 += 32, cur ^= 1) {
    __syncthreads();  // buf cur staged; buf cur^1 free
    if (k0 + 32 < D) STAGE(k0 + 32, cur ^ 1);
    bf16x8 a[4], bb[2];
#pragma unroll
    for (int s = 0; s < 4; ++s)
      a[s] = load8(As[cur] + (wm * 64 + s * 16 + col) * 32 + quad * 8);
#pragma unroll
    for (int t = 0; t < 2; ++t)
      bb[t] = load8(Bs[cur] + (wn * 32 + t * 16 + col) * 32 + quad * 8);
#pragma unroll
    for (int s = 0; s < 4; ++s)
#pragma unroll
      for (int t = 0; t < 2; ++t)
        acc[s][t] = __builtin_amdgcn_mfma_f32_16x16x32_bf16(a[s], bb[t], acc[s][t], 0, 0, 0);
  }
  hbf* wqb = wq + (size_t)b * 16 * T * H;
#pragma unroll
  for (int s = 0; s < 4; ++s) {
    int row = mt * 128 + wm * 64 + s * 16 + quad * 4;
#pragma unroll
    for (int t = 0; t < 2; ++t) {
      int j = jt * 64 + wn * 32 + t * 16 + col;
      int n = j >> 8, h = j & 255;
      hbf* dst = wqb + (size_t)n * T * H + (size_t)row * H + h;
#pragma unroll
      for (int r = 0; r < 4; ++r)
        dst[(size_t)r * H] = __float2bfloat16(acc[s][t][r]);
    }
  }
}

// ------- stage B v2: 32 rows/block (1024 blocks). B-panel (512x32/K-step)
// staged via global_load_lds with 2-phase dbuf; A-frags read from the staged
// panel (the 32 A-rows are a subset of its 512 rows). In-register softmax
// (R1-verified layout), writes attn fp32 (output) + bf16 (stage-C operand).
__global__ __launch_bounds__(256) void attn_k(const hbf* __restrict__ wq,
                                              float* __restrict__ attn_f,
                                              hbf* __restrict__ attn_b) {
  __shared__ __align__(16) hbf Bs[2][512 * 32];  // 64 KB
  __shared__ float redA[4][32];
  __shared__ float redB[4][32];
  int blk = blockIdx.x;        // 1024 blocks: bn*16 + mt
  int bn = blk >> 4, mt = blk & 15;
  int m0 = mt * 32;
  const hbf* Wq = wq + (size_t)bn * T * H;
  int wave = threadIdx.x >> 6, lane = threadIdx.x & 63;
  int col = lane & 15, quad = lane >> 4;

  auto STAGE = [&](int k0, int bi) {
    hbf* Bl = Bs[bi];
#pragma unroll
    for (int j = 0; j < 8; ++j) {  // 32 KB = 32 wave-issues, 8 per wave
      int slot = (wave * 8 + j) * 64 + lane;
      int row = slot >> 2, kc = slot & 3;
      gload16(Wq + (size_t)row * H + k0 + kc * 8, Bl + slot * 8);
    }
  };

  f32x4 acc[2][8] = {};
  STAGE(0, 0);
  int cur = 0;
  for (int k0 = 0; k0 < H; k0 += 32, cur ^= 1) {
    __syncthreads();
    if (k0 + 32 < H) STAGE(k0 + 32, cur ^ 1);
    bf16x8 a[2];
#pragma unroll
    for (int s = 0; s < 2; ++s)
      a[s] = load8(Bs[cur] + (m0 + s * 16 + col) * 32 + quad * 8);
#pragma unroll
    for (int t = 0; t < 8; ++t) {
      bf16x8 bfr = load8(Bs[cur] + (wave * 128 + t * 16 + col) * 32 + quad * 8);
#pragma unroll
      for (int s = 0; s < 2; ++s)
        acc[s][t] = __builtin_amdgcn_mfma_f32_16x16x32_bf16(a[s], bfr, acc[s][t], 0, 0, 0);
    }
  }

  // in-register softmax. C-layout: row_local = s*16+quad*4+r, col = wave*128+t*16+(lane&15)
  float mrow[2][4], inv[2][4];
#pragma unroll
  for (int s = 0; s < 2; ++s)
#pragma unroll
    for (int r = 0; r < 4; ++r) {
      float pm = acc[s][0][r];
#pragma unroll
      for (int t = 1; t < 8; ++t) pm = fmaxf(pm, acc[s][t][r]);
#pragma unroll
      for (int off = 8; off >= 1; off >>= 1) pm = fmaxf(pm, __shfl_xor(pm, off));
      if (col == 0) redA[wave][s * 16 + quad * 4 + r] = pm;
    }
  __syncthreads();
#pragma unroll
  for (int s = 0; s < 2; ++s)
#pragma unroll
    for (int r = 0; r < 4; ++r) {
      int rl = s * 16 + quad * 4 + r;
      mrow[s][r] = fmaxf(fmaxf(redA[0][rl], redA[1][rl]),
                         fmaxf(redA[2][rl], redA[3][rl]));
      float sm = 0.f;
#pragma unroll
      for (int t = 0; t < 8; ++t) {
        float e = __expf(acc[s][t][r] - mrow[s][r]);
        acc[s][t][r] = e;
        sm += e;
      }
#pragma unroll
      for (int off = 8; off >= 1; off >>= 1) sm += __shfl_xor(sm, off);
      if (col == 0) redB[wave][rl] = sm;
    }
  __syncthreads();
#pragma unroll
  for (int s = 0; s < 2; ++s)
#pragma unroll
    for (int r = 0; r < 4; ++r) {
      int rl = s * 16 + quad * 4 + r;
      inv[s][r] = 1.0f / (redB[0][rl] + redB[1][rl] + redB[2][rl] + redB[3][rl]);
    }
#pragma unroll
  for (int s = 0; s < 2; ++s)
#pragma unroll
    for (int r = 0; r < 4; ++r) {
      int rl = s * 16 + quad * 4 + r;
      float iv = inv[s][r];
      size_t base = ((size_t)bn * T + m0 + rl) * T;
      float* dst = attn_f + base;
      hbf* dstb = attn_b + base;
#pragma unroll
      for (int t = 0; t < 8; ++t) {
        int c = wave * 128 + t * 16 + col;
        float p = acc[s][t][r] * iv;
        dst[c] = p;
        dstb[c] = __float2bfloat16(p);
      }
    }
}

// =========== stage C: e[bn][s][d] = sum_t attn[bn][s][t] * x[b][t][d] ========
// 128x128x(BK=32) LDS-tiled, 2-phase dbuf (R2 structure, unchanged).
__global__ __launch_bounds__(256) void gemm_out_tiled(const hbf* __restrict__ attn,
                                                      const hbf* __restrict__ xT,
                                                      float* __restrict__ eout) {
  __shared__ __align__(16) hbf As[2][128 * 32];
  __shared__ __align__(16) hbf Bs[2][128 * 32];
  int idx = blockIdx.x;                 // bn*32 + mt*8 + nt
  int bn = idx >> 5, mt = (idx >> 3) & 3, nt = idx & 7;
  int b = bn >> 4;
  const hbf* A = attn + (size_t)bn * T * T + (size_t)mt * 128 * T;
  const hbf* Bp = xT + (size_t)b * D * T + (size_t)nt * 128 * T;
  float* C = eout + (size_t)bn * T * D;
  int tid = threadIdx.x, wave = tid >> 6, lane = tid & 63;
  int col = lane & 15, quad = lane >> 4;
  int wm = wave & 1, wn = wave >> 1;
  const hbf* stG = (wave < 2) ? A : Bp;
  int ibase = (wave & 1) * 4;
  f32x4 acc[4][4] = {};
  {  // prologue
    hbf* stL = (wave < 2) ? As[0] : Bs[0];
#pragma unroll
    for (int j = 0; j < 4; ++j) {
      int slot = (ibase + j) * 64 + lane;
      int row = slot >> 2, kc = slot & 3;
      gload16(stG + (size_t)row * T + kc * 8, stL + slot * 8);
    }
  }
  int cur = 0;
  for (int k0 = 0; k0 < T; k0 += 32, cur ^= 1) {
    __syncthreads();
    if (k0 + 32 < T) {
      hbf* stL = (wave < 2) ? As[cur ^ 1] : Bs[cur ^ 1];
#pragma unroll
      for (int j = 0; j < 4; ++j) {
        int slot = (ibase + j) * 64 + lane;
        int row = slot >> 2, kc = slot & 3;
        gload16(stG + (size_t)row * T + (k0 + 32) + kc * 8, stL + slot * 8);
      }
    }
    bf16x8 a[4], bb[4];
#pragma unroll
    for (int s = 0; s < 4; ++s)
      a[s] = load8(As[cur] + (wm * 64 + s * 16 + col) * 32 + quad * 8);
#pragma unroll
    for (int t = 0; t < 4; ++t)
      bb[t] = load8(Bs[cur] + (wn * 64 + t * 16 + col) * 32 + quad * 8);
#pragma unroll
    for (int s = 0; s < 4; ++s)
#pragma unroll
      for (int t = 0; t < 4; ++t)
        acc[s][t] = __builtin_amdgcn_mfma_f32_16x16x32_bf16(a[s], bb[t], acc[s][t], 0, 0, 0);
  }
#pragma unroll
  for (int s = 0; s < 4; ++s) {
    int row = mt * 128 + wm * 64 + s * 16 + quad * 4;
#pragma unroll
    for (int t = 0; t < 4; ++t) {
      int d = nt * 128 + wn * 64 + t * 16 + col;
      float* dst = C + (size_t)row * D + d;
#pragma unroll
      for (int r = 0; r < 4; ++r)
        dst[(size_t)r * D] = acc[s][t][r];
    }
  }
}

extern "C" void kernel_launch(void* const* d_in, const int* in_sizes, int n_in,
                              void* d_out, int out_size, void* d_ws, size_t ws_size,
                              hipStream_t stream) {
  const float* x = (const float*)d_in[0];     // [B,T,D] fp32
  const float* w_qs = (const float*)d_in[1];  // [N,D,H] fp32 (w_ks unused per source bug)
  float* e_out = (float*)d_out;               // [B,N,T,D] fp32
  float* attn_out = e_out + E_ELEMS;          // [B,N,T,T] fp32

  char* ws = (char*)d_ws;
  hbf* x_bf = (hbf*)ws;                          // [B,T,D]   4 MB
  hbf* xT   = (hbf*)(ws + (4u << 20));           // [B,D,T]   4 MB
  hbf* wT   = (hbf*)(ws + (8u << 20));           // [N,H,D]   8 MB
  hbf* wq   = (hbf*)(ws + (16u << 20));          // [B*N,T,H] 16 MB
  hbf* attn_b = (hbf*)(ws + (32u << 20));        // [B*N,T,T] 32 MB

  dim3 tb(32, 8);
  cast_bf_k<<<1024, 256, 0, stream>>>(x, (unsigned short*)x_bf, (B * T * D) / 8);
  transpose_cast_k<<<dim3(H / 32, D / 32, N), tb, 0, stream>>>(
      w_qs, (unsigned short*)wT, D, H);
  transpose_cast_k<<<dim3(D / 32, T / 32, B), tb, 0, stream>>>(
      x, (unsigned short*)xT, T, D);
  gemm_wq_tiled<<<1024, 256, 0, stream>>>(x_bf, wT, wq);
  attn_k<<<1024, 256, 0, stream>>>(wq, attn_out, attn_b);
  gemm_out_tiled<<<2048, 256, 0, stream>>>(attn_b, xT, e_out);
}

// Round 5
// 315.003 us; speedup vs baseline: 1.1499x; 1.0654x over previous
//
#include <hip/hip_runtime.h>
#include <hip/hip_bf16.h>

typedef __bf16 bf16x8 __attribute__((ext_vector_type(8)));
typedef unsigned short u16x8 __attribute__((ext_vector_type(8)));
typedef float f32x4 __attribute__((ext_vector_type(4)));
typedef __hip_bfloat16 hbf;

static constexpr int B = 4, T = 512, D = 1024, N = 16, H = 256;
static constexpr size_t E_ELEMS = (size_t)B * N * T * D;    // 33,554,432
static constexpr size_t ATTN_ELEMS = (size_t)B * N * T * T; // 16,777,216

__device__ __forceinline__ bf16x8 load8(const hbf* p) {
  return *reinterpret_cast<const bf16x8*>(p);
}

__device__ __forceinline__ unsigned short f2bf(float f) {
  union { __hip_bfloat16 h; unsigned short u; } cv;
  cv.h = __float2bfloat16(f);
  return cv.u;
}

// async global->LDS, 16B per lane; lds dest must be waveBase + lane*16
__device__ __forceinline__ void gload16(const hbf* g, hbf* l) {
  __builtin_amdgcn_global_load_lds(
      (const __attribute__((address_space(1))) void*)g,
      (__attribute__((address_space(3))) void*)l, 16, 0, 0);
}

// T1: bijective XCD swizzle (8 XCDs, nwg % 8 == 0). Blocks i with equal i%8
// land on one XCD; this remap makes each XCD own a CONTIGUOUS logical range,
// so logical neighbors (which share operand panels) share an L2.
template <int NWG>
__device__ __forceinline__ int xcd_swizzle(int i) {
  return (i & 7) * (NWG / 8) + (i >> 3);
}

// ---------------- fp32 -> bf16 row-major cast (8 elems / thread) -------------
__global__ __launch_bounds__(256) void cast_bf_k(const float* __restrict__ in,
                                                 unsigned short* __restrict__ out,
                                                 int n8) {
  int i = blockIdx.x * 256 + threadIdx.x;
  if (i >= n8) return;
  const float4* p = reinterpret_cast<const float4*>(in) + (size_t)i * 2;
  float4 a = p[0], b = p[1];
  u16x8 v;
  v[0] = f2bf(a.x); v[1] = f2bf(a.y); v[2] = f2bf(a.z); v[3] = f2bf(a.w);
  v[4] = f2bf(b.x); v[5] = f2bf(b.y); v[6] = f2bf(b.z); v[7] = f2bf(b.w);
  reinterpret_cast<u16x8*>(out)[i] = v;
}

// ------------- batched transpose+cast: in[z][r][c] fp32 -> out[z][c][r] bf16 -
__global__ void transpose_cast_k(const float* __restrict__ in,
                                 unsigned short* __restrict__ out, int R, int C) {
  __shared__ unsigned short tile[32][33];
  int z = blockIdx.z;
  int c0 = blockIdx.x * 32, r0 = blockIdx.y * 32;
  const float* inz = in + (size_t)z * R * C;
  unsigned short* outz = out + (size_t)z * R * C;
  int tx = threadIdx.x, ty = threadIdx.y;
  for (int i = ty; i < 32; i += 8)
    tile[i][tx] = f2bf(inz[(size_t)(r0 + i) * C + (c0 + tx)]);
  __syncthreads();
  for (int i = ty; i < 32; i += 8)
    outz[(size_t)(c0 + i) * R + (r0 + tx)] = tile[tx][i];
}

// =========== stage A: wq[b][n][t][h] = sum_d x[b][t][d] * w[n][d][h] =========
// 128x64x(BK=32) LDS-tiled, 2-phase dbuf, 1024 blocks (4/CU).
// T1 swizzle: 64 jt-blocks sharing one 512 KB x-panel colocate per XCD.
__global__ __launch_bounds__(256) void gemm_wq_tiled(const hbf* __restrict__ xb,
                                                     const hbf* __restrict__ wT,
                                                     hbf* __restrict__ wq) {
  __shared__ __align__(16) hbf As[2][128 * 32];
  __shared__ __align__(16) hbf Bs[2][64 * 32];
  int idx = xcd_swizzle<1024>(blockIdx.x);  // b*256 + mt*64 + jt
  int b = idx >> 8, mt = (idx >> 6) & 3, jt = idx & 63;
  const hbf* A = xb + (size_t)b * T * D + (size_t)mt * 128 * D;
  const hbf* Bp = wT + (size_t)jt * 64 * D;
  int tid = threadIdx.x, wave = tid >> 6, lane = tid & 63;
  int col = lane & 15, quad = lane >> 4;
  int wm = wave & 1, wn = wave >> 1;

  auto STAGE = [&](int k0, int bi) {
    if (wave < 2) {  // A: 8 KB = 8 wave-issues, waves 0,1 x 4
#pragma unroll
      for (int j = 0; j < 4; ++j) {
        int slot = (wave * 4 + j) * 64 + lane;
        int row = slot >> 2, kc = slot & 3;
        gload16(A + (size_t)row * D + k0 + kc * 8, As[bi] + slot * 8);
      }
    } else {  // B: 4 KB = 4 wave-issues, waves 2,3 x 2
#pragma unroll
      for (int j = 0; j < 2; ++j) {
        int slot = ((wave - 2) * 2 + j) * 64 + lane;
        int row = slot >> 2, kc = slot & 3;
        gload16(Bp + (size_t)row * D + k0 + kc * 8, Bs[bi] + slot * 8);
      }
    }
  };

  f32x4 acc[4][2] = {};
  STAGE(0, 0);
  int cur = 0;
  for (int k0 = 0; k0 < D; k0 += 32, cur ^= 1) {
    __syncthreads();  // buf cur staged; buf cur^1 free
    if (k0 + 32 < D) STAGE(k0 + 32, cur ^ 1);
    bf16x8 a[4], bb[2];
#pragma unroll
    for (int s = 0; s < 4; ++s)
      a[s] = load8(As[cur] + (wm * 64 + s * 16 + col) * 32 + quad * 8);
#pragma unroll
    for (int t = 0; t < 2; ++t)
      bb[t] = load8(Bs[cur] + (wn * 32 + t * 16 + col) * 32 + quad * 8);
#pragma unroll
    for (int s = 0; s < 4; ++s)
#pragma unroll
      for (int t = 0; t < 2; ++t)
        acc[s][t] = __builtin_amdgcn_mfma_f32_16x16x32_bf16(a[s], bb[t], acc[s][t], 0, 0, 0);
  }
  hbf* wqb = wq + (size_t)b * 16 * T * H;
#pragma unroll
  for (int s = 0; s < 4; ++s) {
    int row = mt * 128 + wm * 64 + s * 16 + quad * 4;
#pragma unroll
    for (int t = 0; t < 2; ++t) {
      int j = jt * 64 + wn * 32 + t * 16 + col;
      int n = j >> 8, h = j & 255;
      hbf* dst = wqb + (size_t)n * T * H + (size_t)row * H + h;
#pragma unroll
      for (int r = 0; r < 4; ++r)
        dst[(size_t)r * H] = __float2bfloat16(acc[s][t][r]);
    }
  }
}

// ------- stage B v2: 32 rows/block (1024 blocks). B-panel (512x32/K-step)
// staged via global_load_lds with 2-phase dbuf; in-register softmax.
// T1 swizzle: 16 mt-blocks sharing one 256 KB Wq panel colocate per XCD;
// XCD c owns bn in [8c, 8c+8) — matches gemm_out's consumer mapping.
__global__ __launch_bounds__(256) void attn_k(const hbf* __restrict__ wq,
                                              float* __restrict__ attn_f,
                                              hbf* __restrict__ attn_b) {
  __shared__ __align__(16) hbf Bs[2][512 * 32];  // 64 KB
  __shared__ float redA[4][32];
  __shared__ float redB[4][32];
  int blk = xcd_swizzle<1024>(blockIdx.x);  // bn*16 + mt
  int bn = blk >> 4, mt = blk & 15;
  int m0 = mt * 32;
  const hbf* Wq = wq + (size_t)bn * T * H;
  int wave = threadIdx.x >> 6, lane = threadIdx.x & 63;
  int col = lane & 15, quad = lane >> 4;

  auto STAGE = [&](int k0, int bi) {
    hbf* Bl = Bs[bi];
#pragma unroll
    for (int j = 0; j < 8; ++j) {  // 32 KB = 32 wave-issues, 8 per wave
      int slot = (wave * 8 + j) * 64 + lane;
      int row = slot >> 2, kc = slot & 3;
      gload16(Wq + (size_t)row * H + k0 + kc * 8, Bl + slot * 8);
    }
  };

  f32x4 acc[2][8] = {};
  STAGE(0, 0);
  int cur = 0;
  for (int k0 = 0; k0 < H; k0 += 32, cur ^= 1) {
    __syncthreads();
    if (k0 + 32 < H) STAGE(k0 + 32, cur ^ 1);
    bf16x8 a[2];
#pragma unroll
    for (int s = 0; s < 2; ++s)
      a[s] = load8(Bs[cur] + (m0 + s * 16 + col) * 32 + quad * 8);
#pragma unroll
    for (int t = 0; t < 8; ++t) {
      bf16x8 bfr = load8(Bs[cur] + (wave * 128 + t * 16 + col) * 32 + quad * 8);
#pragma unroll
      for (int s = 0; s < 2; ++s)
        acc[s][t] = __builtin_amdgcn_mfma_f32_16x16x32_bf16(a[s], bfr, acc[s][t], 0, 0, 0);
    }
  }

  // in-register softmax. C-layout: row_local = s*16+quad*4+r, col = wave*128+t*16+(lane&15)
  float mrow[2][4], inv[2][4];
#pragma unroll
  for (int s = 0; s < 2; ++s)
#pragma unroll
    for (int r = 0; r < 4; ++r) {
      float pm = acc[s][0][r];
#pragma unroll
      for (int t = 1; t < 8; ++t) pm = fmaxf(pm, acc[s][t][r]);
#pragma unroll
      for (int off = 8; off >= 1; off >>= 1) pm = fmaxf(pm, __shfl_xor(pm, off));
      if (col == 0) redA[wave][s * 16 + quad * 4 + r] = pm;
    }
  __syncthreads();
#pragma unroll
  for (int s = 0; s < 2; ++s)
#pragma unroll
    for (int r = 0; r < 4; ++r) {
      int rl = s * 16 + quad * 4 + r;
      mrow[s][r] = fmaxf(fmaxf(redA[0][rl], redA[1][rl]),
                         fmaxf(redA[2][rl], redA[3][rl]));
      float sm = 0.f;
#pragma unroll
      for (int t = 0; t < 8; ++t) {
        float e = __expf(acc[s][t][r] - mrow[s][r]);
        acc[s][t][r] = e;
        sm += e;
      }
#pragma unroll
      for (int off = 8; off >= 1; off >>= 1) sm += __shfl_xor(sm, off);
      if (col == 0) redB[wave][rl] = sm;
    }
  __syncthreads();
#pragma unroll
  for (int s = 0; s < 2; ++s)
#pragma unroll
    for (int r = 0; r < 4; ++r) {
      int rl = s * 16 + quad * 4 + r;
      inv[s][r] = 1.0f / (redB[0][rl] + redB[1][rl] + redB[2][rl] + redB[3][rl]);
    }
#pragma unroll
  for (int s = 0; s < 2; ++s)
#pragma unroll
    for (int r = 0; r < 4; ++r) {
      int rl = s * 16 + quad * 4 + r;
      float iv = inv[s][r];
      size_t base = ((size_t)bn * T + m0 + rl) * T;
      float* dst = attn_f + base;
      hbf* dstb = attn_b + base;
#pragma unroll
      for (int t = 0; t < 8; ++t) {
        int c = wave * 128 + t * 16 + col;
        float p = acc[s][t][r] * iv;
        dst[c] = p;
        dstb[c] = __float2bfloat16(p);
      }
    }
}

// =========== stage C: e[bn][s][d] = sum_t attn[bn][s][t] * x[b][t][d] ========
// 128x128x(BK=32) LDS-tiled, 2-phase dbuf. T1 swizzle: the 8 nt-blocks
// sharing one 128 KB attn_b A-panel colocate per XCD (was: spread over all 8
// XCDs -> 8x L3 re-fetch). XCD c owns bn in [8c, 8c+8) — same range attn_k
// produced into this XCD's L2.
__global__ __launch_bounds__(256) void gemm_out_tiled(const hbf* __restrict__ attn,
                                                      const hbf* __restrict__ xT,
                                                      float* __restrict__ eout) {
  __shared__ __align__(16) hbf As[2][128 * 32];
  __shared__ __align__(16) hbf Bs[2][128 * 32];
  int idx = xcd_swizzle<2048>(blockIdx.x);  // bn*32 + mt*8 + nt
  int bn = idx >> 5, mt = (idx >> 3) & 3, nt = idx & 7;
  int b = bn >> 4;
  const hbf* A = attn + (size_t)bn * T * T + (size_t)mt * 128 * T;
  const hbf* Bp = xT + (size_t)b * D * T + (size_t)nt * 128 * T;
  float* C = eout + (size_t)bn * T * D;
  int tid = threadIdx.x, wave = tid >> 6, lane = tid & 63;
  int col = lane & 15, quad = lane >> 4;
  int wm = wave & 1, wn = wave >> 1;
  const hbf* stG = (wave < 2) ? A : Bp;
  int ibase = (wave & 1) * 4;
  f32x4 acc[4][4] = {};
  {  // prologue
    hbf* stL = (wave < 2) ? As[0] : Bs[0];
#pragma unroll
    for (int j = 0; j < 4; ++j) {
      int slot = (ibase + j) * 64 + lane;
      int row = slot >> 2, kc = slot & 3;
      gload16(stG + (size_t)row * T + kc * 8, stL + slot * 8);
    }
  }
  int cur = 0;
  for (int k0 = 0; k0 < T; k0 += 32, cur ^= 1) {
    __syncthreads();
    if (k0 + 32 < T) {
      hbf* stL = (wave < 2) ? As[cur ^ 1] : Bs[cur ^ 1];
#pragma unroll
      for (int j = 0; j < 4; ++j) {
        int slot = (ibase + j) * 64 + lane;
        int row = slot >> 2, kc = slot & 3;
        gload16(stG + (size_t)row * T + (k0 + 32) + kc * 8, stL + slot * 8);
      }
    }
    bf16x8 a[4], bb[4];
#pragma unroll
    for (int s = 0; s < 4; ++s)
      a[s] = load8(As[cur] + (wm * 64 + s * 16 + col) * 32 + quad * 8);
#pragma unroll
    for (int t = 0; t < 4; ++t)
      bb[t] = load8(Bs[cur] + (wn * 64 + t * 16 + col) * 32 + quad * 8);
#pragma unroll
    for (int s = 0; s < 4; ++s)
#pragma unroll
      for (int t = 0; t < 4; ++t)
        acc[s][t] = __builtin_amdgcn_mfma_f32_16x16x32_bf16(a[s], bb[t], acc[s][t], 0, 0, 0);
  }
#pragma unroll
  for (int s = 0; s < 4; ++s) {
    int row = mt * 128 + wm * 64 + s * 16 + quad * 4;
#pragma unroll
    for (int t = 0; t < 4; ++t) {
      int d = nt * 128 + wn * 64 + t * 16 + col;
      float* dst = C + (size_t)row * D + d;
#pragma unroll
      for (int r = 0; r < 4; ++r)
        dst[(size_t)r * D] = acc[s][t][r];
    }
  }
}

extern "C" void kernel_launch(void* const* d_in, const int* in_sizes, int n_in,
                              void* d_out, int out_size, void* d_ws, size_t ws_size,
                              hipStream_t stream) {
  const float* x = (const float*)d_in[0];     // [B,T,D] fp32
  const float* w_qs = (const float*)d_in[1];  // [N,D,H] fp32 (w_ks unused per source bug)
  float* e_out = (float*)d_out;               // [B,N,T,D] fp32
  float* attn_out = e_out + E_ELEMS;          // [B,N,T,T] fp32

  char* ws = (char*)d_ws;
  hbf* x_bf = (hbf*)ws;                          // [B,T,D]   4 MB
  hbf* xT   = (hbf*)(ws + (4u << 20));           // [B,D,T]   4 MB
  hbf* wT   = (hbf*)(ws + (8u << 20));           // [N,H,D]   8 MB
  hbf* wq   = (hbf*)(ws + (16u << 20));          // [B*N,T,H] 16 MB
  hbf* attn_b = (hbf*)(ws + (32u << 20));        // [B*N,T,T] 32 MB

  dim3 tb(32, 8);
  cast_bf_k<<<1024, 256, 0, stream>>>(x, (unsigned short*)x_bf, (B * T * D) / 8);
  transpose_cast_k<<<dim3(H / 32, D / 32, N), tb, 0, stream>>>(
      w_qs, (unsigned short*)wT, D, H);
  transpose_cast_k<<<dim3(D / 32, T / 32, B), tb, 0, stream>>>(
      x, (unsigned short*)xT, T, D);
  gemm_wq_tiled<<<1024, 256, 0, stream>>>(x_bf, wT, wq);
  attn_k<<<1024, 256, 0, stream>>>(wq, attn_out, attn_b);
  gemm_out_tiled<<<2048, 256, 0, stream>>>(attn_b, xT, e_out);
}